// Round 2
// baseline (2612.830 us; speedup 1.0000x reference)
//
#include <hip/hip_runtime.h>
#include <hip/hip_bf16.h>
#include <cstdint>

#define NHW 65536
#define NSQ 32768

// workspace layout (float slots)
static constexpr size_t OFF_AQ  = 0;          // (4,64,256,128) conv1x1_q at nonanchor (squeezed)
static constexpr size_t OFF_AK  = 8388608;    // (4,64,256,128) conv1x1_k at anchor (squeezed)
static constexpr size_t OFF_AV  = 16777216;   // (4,64,256,256) conv1x1_v full res
static constexpr size_t OFF_EK  = 33554432;   // (4,64,256,128) exp(k_dw) squeezed
static constexpr size_t OFF_VD  = 41943040;   // (4,64,256,128) v_dw squeezed
static constexpr size_t OFF_ATT = 50331648;   // (4,64,256,128) att squeezed (nonanchor)
static constexpr size_t OFF_CTX = 58720256;   // 4*4*16*16
static constexpr size_t OFF_Z   = 58724352;   // 4*64
static constexpr size_t OFF_RWT = 58724608;   // 204800 transposed r_w
static constexpr size_t MB2_US  = 67108864;   // ushort offset of mbuf2 (mbuf at 0) - phases don't overlap

__device__ __forceinline__ float geluf(float x) {
  return 0.5f * x * (1.0f + erff(x * 0.70710678118654752440f));
}
__device__ __forceinline__ unsigned short f2bf(float f) {
  union { float f; uint32_t u; } v; v.f = f;
  uint32_t x = v.u;
  uint32_t r = x + 0x7fffu + ((x >> 16) & 1u);
  return (unsigned short)(r >> 16);
}
__device__ __forceinline__ float bf2f(unsigned short u) {
  union { uint32_t i; float f; } v; v.i = ((uint32_t)u) << 16; return v.f;
}

// K0: transpose r_w[o][c][kh][kw] -> rwt[((og*64+c)*25+t)*32+oo]  (o = og*32+oo)
__global__ void __launch_bounds__(256) k0_rwt(const float* __restrict__ rw, float* __restrict__ ws) {
  int idx = blockIdx.x * 256 + threadIdx.x;   // 204800 total
  int oo = idx & 31;
  int rest = idx >> 5;
  int t = rest % 25;
  int rest2 = rest / 25;
  int c = rest2 & 63;
  int og = rest2 >> 6;
  ws[OFF_RWT + idx] = rw[(((og * 32 + oo) * 64 + c) * 25) + t];
}

// K1: 1x1 convs. q at nonanchor((i+j)%2==0), k at anchor, v everywhere.
__global__ void __launch_bounds__(256) k1_qkv(
    const float* __restrict__ x1, const float* __restrict__ x2,
    const float* __restrict__ q1w, const float* __restrict__ q1b,
    const float* __restrict__ k1w, const float* __restrict__ k1b,
    const float* __restrict__ v1w, const float* __restrict__ v1b,
    float* ws) {
  __shared__ float wq[4096], wk[4096], wv[4096];
  int tid = threadIdx.x;
  for (int idx = tid; idx < 4096; idx += 256) {
    int o = idx >> 6, c = idx & 63;        // coalesced global reads
    wq[c * 64 + o] = q1w[o * 64 + c];
    wk[c * 64 + o] = k1w[o * 64 + c];
    wv[c * 64 + o] = v1w[o * 64 + c];
  }
  __syncthreads();
  int b = blockIdx.x >> 8, i = blockIdx.x & 255;
  int w = tid >> 6, l = tid & 63;
  int j = (((w >> 1) * 64 + l) << 1) | (w & 1);  // wave-uniform column parity
  int par = (i + j) & 1;                          // 1 = anchor -> k
  const float* wsel = par ? wk : wq;
  const float* bsel = par ? k1b : q1b;
  float acc[64];
#pragma unroll
  for (int o = 0; o < 64; o++) acc[o] = bsel[o];
  const float* xp = x1 + ((size_t)b * 64) * NHW + i * 256 + j;
  for (int c = 0; c < 64; c++) {
    float v = xp[(size_t)c * NHW];
    const float* wr = wsel + c * 64;
#pragma unroll
    for (int o = 0; o < 64; o++) acc[o] += wr[o] * v;
  }
  {
    float* dst = ws + (par ? OFF_AK : OFF_AQ) + ((size_t)b * 64) * NSQ + i * 128 + (j >> 1);
#pragma unroll
    for (int o = 0; o < 64; o++) dst[(size_t)o * NSQ] = acc[o];
  }
#pragma unroll
  for (int o = 0; o < 64; o++) acc[o] = v1b[o];
  const float* xp2 = x2 + ((size_t)b * 64) * NHW + i * 256 + j;
  for (int c = 0; c < 64; c++) {
    float v = xp2[(size_t)c * NHW];
    const float* wr = wv + c * 64;
#pragma unroll
    for (int o = 0; o < 64; o++) acc[o] += wr[o] * v;
  }
  float* dv = ws + OFF_AV + ((size_t)b * 64) * NHW + i * 256 + j;
#pragma unroll
  for (int o = 0; o < 64; o++) dv[(size_t)o * NHW] = acc[o];
}

// K2: k depthwise (5 real taps + bias correction) -> exp; v depthwise (9 taps, full res);
// accumulate Z[b,c] = sum exp(kdw)
__global__ void __launch_bounds__(256) k2_dw(
    float* ws,
    const float* __restrict__ kw2, const float* __restrict__ kb2, const float* __restrict__ kb1,
    const float* __restrict__ vw2, const float* __restrict__ vb2) {
  int bid = blockIdx.x;                 // 4*64*128
  int b = bid >> 13, c = (bid >> 7) & 63, ip = bid & 127;
  int tid = threadIdx.x;
  int i = ip * 2 + (tid >> 7);
  int jp = tid & 127;
  int s = 1 - (i & 1);                  // anchor: col = 2*jp + s
  int j = 2 * jp + s;
  const float* AK = ws + OFF_AK + ((size_t)(b * 64 + c)) * NSQ;
  const float* w9 = kw2 + c * 9;
  float acc = kb2[c] + w9[4] * AK[i * 128 + jp];
  int cl = jp - 1 + s, cr = jp + s;
  if (i > 0) {
    const float* r = AK + (i - 1) * 128;
    if (cl >= 0)   acc += w9[0] * r[cl];
    if (cr <= 127) acc += w9[2] * r[cr];
  }
  if (i < 255) {
    const float* r = AK + (i + 1) * 128;
    if (cl >= 0)   acc += w9[6] * r[cl];
    if (cr <= 127) acc += w9[8] * r[cr];
  }
  float bs = 0.f;
  if (i > 0)   bs += w9[1];
  if (i < 255) bs += w9[7];
  if (j > 0)   bs += w9[3];
  if (j < 255) bs += w9[5];
  acc += kb1[c] * bs;                   // masked neighbors contribute conv1 bias only
  float ek = expf(acc);
  ws[OFF_EK + ((size_t)(b * 64 + c)) * NSQ + i * 128 + jp] = ek;

  const float* AV = ws + OFF_AV + ((size_t)(b * 64 + c)) * NHW;
  const float* vw = vw2 + c * 9;
  float av = vb2[c];
#pragma unroll
  for (int kh = 0; kh < 3; kh++) {
    int r = i - 1 + kh;
    if (r < 0 || r > 255) continue;
    const float* rp = AV + r * 256;
#pragma unroll
    for (int kwd = 0; kwd < 3; kwd++) {
      int u = j - 1 + kwd;
      if (u < 0 || u > 255) continue;
      av += vw[kh * 3 + kwd] * rp[u];
    }
  }
  ws[OFF_VD + ((size_t)(b * 64 + c)) * NSQ + i * 128 + jp] = av;

  __shared__ float red[256];
  red[tid] = ek;
  __syncthreads();
#pragma unroll
  for (int off = 128; off > 0; off >>= 1) {
    if (tid < off) red[tid] += red[tid + off];
    __syncthreads();
  }
  if (tid == 0) atomicAdd(ws + OFF_Z + (b * 64 + c), red[0]);
}

// K3: ctx_raw[b,h,d,e] = sum_n ek[b,h*16+d,n] * vdw[b,h*16+e,n]
__global__ void __launch_bounds__(256) k3_ctx(float* ws) {
  int bid = blockIdx.x;                 // 4*4*8
  int b = bid >> 5, h = (bid >> 3) & 3, ch = bid & 7;
  int n0 = ch * 4096;
  int tid = threadIdx.x;
  int d = tid >> 4, e = tid & 15;
  __shared__ float ekt[16][260];
  __shared__ float vdt[16][260];
  const float* ekb = ws + OFF_EK + ((size_t)(b * 64 + h * 16)) * NSQ + n0;
  const float* vdb = ws + OFF_VD + ((size_t)(b * 64 + h * 16)) * NSQ + n0;
  float acc = 0.f;
  for (int sub = 0; sub < 16; sub++) {
    __syncthreads();
#pragma unroll
    for (int r = 0; r < 16; r++) {
      ekt[r][tid] = ekb[(size_t)r * NSQ + sub * 256 + tid];
      vdt[r][tid] = vdb[(size_t)r * NSQ + sub * 256 + tid];
    }
    __syncthreads();
#pragma unroll 8
    for (int x = 0; x < 256; x++) acc += ekt[d][x] * vdt[e][x];
  }
  atomicAdd(ws + OFF_CTX + ((b * 4 + h) * 16 + d) * 16 + e, acc);
}

// K4: q depthwise + softmax over d, att[e] = sum_d (ctx_raw/Z)[d,e]*qsoft[d], store squeezed
__global__ void __launch_bounds__(256) k4_att(
    float* ws,
    const float* __restrict__ qw2, const float* __restrict__ qb2, const float* __restrict__ qb1) {
  int b = blockIdx.x >> 7, ip = blockIdx.x & 127;
  int tid = threadIdx.x;
  int i = ip * 2 + (tid >> 7);
  int jp = tid & 127;
  __shared__ float ctxn[1024];
  for (int idx = tid; idx < 1024; idx += 256)
    ctxn[idx] = ws[OFF_CTX + b * 1024 + idx] / ws[OFF_Z + b * 64 + (idx >> 4)];
  __syncthreads();
  int s = i & 1;                        // nonanchor: col = 2*jp + s
  int j = 2 * jp + s;
  int cl = jp - 1 + s, cr = jp + s;
  for (int h = 0; h < 4; h++) {
    float qv[16];
#pragma unroll
    for (int dc = 0; dc < 16; dc++) {
      int c = h * 16 + dc;
      const float* AQ = ws + OFF_AQ + ((size_t)(b * 64 + c)) * NSQ;
      const float* w9 = qw2 + c * 9;
      float acc = qb2[c] + w9[4] * AQ[i * 128 + jp];
      if (i > 0) {
        const float* r = AQ + (i - 1) * 128;
        if (cl >= 0)   acc += w9[0] * r[cl];
        if (cr <= 127) acc += w9[2] * r[cr];
      }
      if (i < 255) {
        const float* r = AQ + (i + 1) * 128;
        if (cl >= 0)   acc += w9[6] * r[cl];
        if (cr <= 127) acc += w9[8] * r[cr];
      }
      float bs = 0.f;
      if (i > 0)   bs += w9[1];
      if (i < 255) bs += w9[7];
      if (j > 0)   bs += w9[3];
      if (j < 255) bs += w9[5];
      qv[dc] = acc + qb1[c] * bs;
    }
    float mx = qv[0];
#pragma unroll
    for (int dc = 1; dc < 16; dc++) mx = fmaxf(mx, qv[dc]);
    float sum = 0.f;
#pragma unroll
    for (int dc = 0; dc < 16; dc++) { qv[dc] = expf(qv[dc] - mx); sum += qv[dc]; }
    float inv = 1.0f / sum;
#pragma unroll
    for (int e = 0; e < 16; e++) {
      float a = 0.f;
#pragma unroll
      for (int dc = 0; dc < 16; dc++) a += ctxn[h * 256 + dc * 16 + e] * qv[dc];
      ws[OFF_ATT + ((size_t)(b * 64 + h * 16 + e)) * NSQ + i * 128 + jp] = a * inv;
    }
  }
}

// K5: 5x5 conv 64->128ch over checkerboard-sparse att (squeezed input, ~12.5 valid taps).
// Each thread owns a horizontal pixel pair; acc0/acc1 indexed by pixel parity (tap->acc is
// compile-time uniform: parity (kh+kw)&1).
__global__ void __launch_bounds__(256) k5_conv5(
    const float* __restrict__ ws, const float* __restrict__ rb, float* __restrict__ out) {
  int tile = blockIdx.x;                // 16x8 tiles of 16x32 pixels
  int og = blockIdx.y, b = blockIdx.z;
  int i0 = (tile >> 3) * 16, j0 = (tile & 7) * 32;
  int c0 = (j0 >> 1) - 1;
  int tid = threadIdx.x;
  int ty = tid >> 4, txp = tid & 15, tx2 = txp * 2;
  int i = i0 + ty;
  __shared__ float attL[12160];         // 32ch x 20rows x 19cols'
  const float* rwt = ws + OFF_RWT;
  float acc0[32], acc1[32];
#pragma unroll
  for (int o = 0; o < 32; o++) { acc0[o] = 0.f; acc1[o] = 0.f; }
  for (int cb = 0; cb < 64; cb += 32) {
    __syncthreads();
    for (int idx = tid; idx < 12160; idx += 256) {
      int c = idx / 380;
      int rem = idx - c * 380;
      int rr = rem / 19;
      int cp = rem - rr * 19;
      int r = i0 - 2 + rr;
      int ca = c0 + cp;
      float v = 0.f;
      if (r >= 0 && r < 256 && ca >= 0 && ca < 128)
        v = ws[OFF_ATT + ((size_t)(b * 64 + cb + c)) * NSQ + r * 128 + ca];
      attL[idx] = v;
    }
    __syncthreads();
    for (int c = 0; c < 32; c++) {
      const float* ap = attL + c * 380;
      const float* wpc = rwt + ((size_t)((og * 64 + cb + c) * 25)) * 32;
#pragma unroll
      for (int kh = 0; kh < 5; kh++) {
        int rr = ty + kh;
        int sp = (i + kh) & 1;          // input-row parity
        const float* apr = ap + rr * 19;
#pragma unroll
        for (int kw = 0; kw < 5; kw++) {
          int isB = (kw - sp) & 1;
          int lcol = (tx2 + isB + kw - sp) >> 1;
          float v = apr[lcol];
          const float* wp = wpc + (kh * 5 + kw) * 32;
          if (((kh + kw) & 1) == 0) {
#pragma unroll
            for (int o = 0; o < 32; o++) acc0[o] += wp[o] * v;
          } else {
#pragma unroll
            for (int o = 0; o < 32; o++) acc1[o] += wp[o] * v;
          }
        }
      }
    }
  }
  int colE = j0 + tx2 + (i & 1);        // pixel with (i+j) even
  int colO = j0 + tx2 + 1 - (i & 1);
  size_t base = ((size_t)(b * 128 + og * 32)) * NHW + (size_t)i * 256;
#pragma unroll
  for (int o = 0; o < 32; o++) {
    float bo = rb[og * 32 + o];
    out[base + (size_t)o * NHW + colE] = acc0[o] + bo;
    out[base + (size_t)o * NHW + colO] = acc1[o] + bo;
  }
}

// K6: m1 = gelu(conv1x1 128->256) ; fp32 in (d_out), bf16 out
__global__ void __launch_bounds__(256) k6_m1(
    const float* __restrict__ attn, const float* __restrict__ m1w, const float* __restrict__ m1b,
    unsigned short* __restrict__ mb) {
  int n0 = blockIdx.x * 64;
  int og = blockIdx.y, b = blockIdx.z;
  int tid = threadIdx.x;
  int ot = tid >> 4, pt = tid & 15;
  __shared__ __align__(16) float aL[2048];
  __shared__ __align__(16) float wL[32 * 68];
  float acc[4][4];
#pragma unroll
  for (int x = 0; x < 4; x++)
#pragma unroll
    for (int y = 0; y < 4; y++) acc[x][y] = 0.f;
  for (int cc = 0; cc < 128; cc += 32) {
    __syncthreads();
#pragma unroll
    for (int k = 0; k < 8; k++) {
      int idx = k * 256 + tid;
      int ci = idx >> 6, p = idx & 63;
      aL[ci * 64 + p] = attn[((size_t)(b * 128 + cc + ci)) * NHW + n0 + p];
      int o = idx >> 5, ci2 = idx & 31;
      wL[ci2 * 68 + o] = m1w[(og * 64 + o) * 128 + cc + ci2];
    }
    __syncthreads();
    for (int ci = 0; ci < 32; ci++) {
      float4 a4 = *(const float4*)(aL + ci * 64 + pt * 4);
      float4 w4 = *(const float4*)(wL + ci * 68 + ot * 4);
      acc[0][0] += w4.x * a4.x; acc[0][1] += w4.x * a4.y; acc[0][2] += w4.x * a4.z; acc[0][3] += w4.x * a4.w;
      acc[1][0] += w4.y * a4.x; acc[1][1] += w4.y * a4.y; acc[1][2] += w4.y * a4.z; acc[1][3] += w4.y * a4.w;
      acc[2][0] += w4.z * a4.x; acc[2][1] += w4.z * a4.y; acc[2][2] += w4.z * a4.z; acc[2][3] += w4.z * a4.w;
      acc[3][0] += w4.w * a4.x; acc[3][1] += w4.w * a4.y; acc[3][2] += w4.w * a4.z; acc[3][3] += w4.w * a4.w;
    }
  }
#pragma unroll
  for (int oi = 0; oi < 4; oi++) {
    int o = og * 64 + ot * 4 + oi;
    float bo = m1b[o];
    ushort4 u;
    u.x = f2bf(geluf(acc[oi][0] + bo));
    u.y = f2bf(geluf(acc[oi][1] + bo));
    u.z = f2bf(geluf(acc[oi][2] + bo));
    u.w = f2bf(geluf(acc[oi][3] + bo));
    *(ushort4*)(mb + ((size_t)(b * 256 + o)) * NHW + n0 + pt * 4) = u;
  }
}

// K7: m2 = gelu(depthwise 3x3 on 256ch), bf16 -> bf16
__global__ void __launch_bounds__(256) k7_m2(
    const unsigned short* __restrict__ mb, const float* __restrict__ m2w,
    const float* __restrict__ m2b, unsigned short* __restrict__ mb2) {
  int bid = blockIdx.x;
  int b = bid >> 16, c = (bid >> 8) & 255, i = bid & 255;
  int j = threadIdx.x;
  const unsigned short* base = mb + ((size_t)(b * 256 + c)) * NHW;
  const float* w9 = m2w + c * 9;
  float acc = m2b[c];
#pragma unroll
  for (int kh = 0; kh < 3; kh++) {
    int r = i - 1 + kh;
    if (r < 0 || r > 255) continue;
#pragma unroll
    for (int kw = 0; kw < 3; kw++) {
      int u = j - 1 + kw;
      if (u < 0 || u > 255) continue;
      acc += w9[kh * 3 + kw] * bf2f(base[r * 256 + u]);
    }
  }
  mb2[((size_t)(b * 256 + c)) * NHW + i * 256 + j] = f2bf(geluf(acc));
}

// K8: out = attention + conv1x1(m2, 256->128) + m3_b ; bf16 in, fp32 in/out (d_out)
__global__ void __launch_bounds__(256) k8_m3(
    const unsigned short* __restrict__ mb2, const float* __restrict__ m3w,
    const float* __restrict__ m3b, float* __restrict__ out) {
  int n0 = blockIdx.x * 64;
  int og = blockIdx.y, b = blockIdx.z;
  int tid = threadIdx.x;
  int ot = tid >> 4, pt = tid & 15;
  __shared__ __align__(16) float aL[2048];
  __shared__ __align__(16) float wL[32 * 68];
  float acc[4][4];
#pragma unroll
  for (int x = 0; x < 4; x++)
#pragma unroll
    for (int y = 0; y < 4; y++) acc[x][y] = 0.f;
  for (int cc = 0; cc < 256; cc += 32) {
    __syncthreads();
#pragma unroll
    for (int k = 0; k < 2; k++) {
      int e4 = (k * 256 + tid) * 4;
      int ci = e4 >> 6, p0 = e4 & 63;
      const ushort4 uv = *(const ushort4*)(mb2 + ((size_t)(b * 256 + cc + ci)) * NHW + n0 + p0);
      aL[ci * 64 + p0 + 0] = bf2f(uv.x);
      aL[ci * 64 + p0 + 1] = bf2f(uv.y);
      aL[ci * 64 + p0 + 2] = bf2f(uv.z);
      aL[ci * 64 + p0 + 3] = bf2f(uv.w);
    }
#pragma unroll
    for (int k = 0; k < 8; k++) {
      int idx = k * 256 + tid;
      int o = idx >> 5, ci2 = idx & 31;
      wL[ci2 * 68 + o] = m3w[(og * 64 + o) * 256 + cc + ci2];
    }
    __syncthreads();
    for (int ci = 0; ci < 32; ci++) {
      float4 a4 = *(const float4*)(aL + ci * 64 + pt * 4);
      float4 w4 = *(const float4*)(wL + ci * 68 + ot * 4);
      acc[0][0] += w4.x * a4.x; acc[0][1] += w4.x * a4.y; acc[0][2] += w4.x * a4.z; acc[0][3] += w4.x * a4.w;
      acc[1][0] += w4.y * a4.x; acc[1][1] += w4.y * a4.y; acc[1][2] += w4.y * a4.z; acc[1][3] += w4.y * a4.w;
      acc[2][0] += w4.z * a4.x; acc[2][1] += w4.z * a4.y; acc[2][2] += w4.z * a4.z; acc[2][3] += w4.z * a4.w;
      acc[3][0] += w4.w * a4.x; acc[3][1] += w4.w * a4.y; acc[3][2] += w4.w * a4.z; acc[3][3] += w4.w * a4.w;
    }
  }
#pragma unroll
  for (int oi = 0; oi < 4; oi++) {
    int o = og * 64 + ot * 4 + oi;
    float bo = m3b[o];
    size_t addr = ((size_t)(b * 128 + o)) * NHW + n0 + pt * 4;
    float4 prev = *(const float4*)(out + addr);
    float4 res;
    res.x = prev.x + acc[oi][0] + bo;
    res.y = prev.y + acc[oi][1] + bo;
    res.z = prev.z + acc[oi][2] + bo;
    res.w = prev.w + acc[oi][3] + bo;
    *(float4*)(out + addr) = res;
  }
}

extern "C" void kernel_launch(void* const* d_in, const int* in_sizes, int n_in,
                              void* d_out, int out_size, void* d_ws, size_t ws_size,
                              hipStream_t stream) {
  const float* x1  = (const float*)d_in[0];
  const float* x2  = (const float*)d_in[1];
  const float* q1w = (const float*)d_in[2];  const float* q1b = (const float*)d_in[3];
  const float* q2w = (const float*)d_in[4];  const float* q2b = (const float*)d_in[5];
  const float* k1w = (const float*)d_in[6];  const float* k1b = (const float*)d_in[7];
  const float* k2w = (const float*)d_in[8];  const float* k2b = (const float*)d_in[9];
  const float* v1w = (const float*)d_in[10]; const float* v1b = (const float*)d_in[11];
  const float* v2w = (const float*)d_in[12]; const float* v2b = (const float*)d_in[13];
  const float* rw  = (const float*)d_in[14]; const float* rb  = (const float*)d_in[15];
  const float* m1w = (const float*)d_in[16]; const float* m1b = (const float*)d_in[17];
  const float* m2w = (const float*)d_in[18]; const float* m2b = (const float*)d_in[19];
  const float* m3w = (const float*)d_in[20]; const float* m3b = (const float*)d_in[21];
  float* ws = (float*)d_ws;
  float* out = (float*)d_out;
  unsigned short* mb  = (unsigned short*)d_ws;
  unsigned short* mb2 = (unsigned short*)d_ws + MB2_US;

  (void)hipMemsetAsync((char*)d_ws + OFF_CTX * sizeof(float), 0, (4096 + 256) * sizeof(float), stream);
  k0_rwt<<<800, 256, 0, stream>>>(rw, ws);
  k1_qkv<<<1024, 256, 0, stream>>>(x1, x2, q1w, q1b, k1w, k1b, v1w, v1b, ws);
  k2_dw<<<32768, 256, 0, stream>>>(ws, k2w, k2b, k1b, v2w, v2b);
  k3_ctx<<<128, 256, 0, stream>>>(ws);
  k4_att<<<512, 256, 0, stream>>>(ws, q2w, q2b, q1b);
  k5_conv5<<<dim3(128, 4, 4), 256, 0, stream>>>(ws, rb, out);
  k6_m1<<<dim3(1024, 4, 4), 256, 0, stream>>>(out, m1w, m1b, mb);
  k7_m2<<<262144, 256, 0, stream>>>(mb, m2w, m2b, mb2);
  k8_m3<<<dim3(1024, 2, 4), 256, 0, stream>>>(mb2, m3w, m3b, out);
}

// Round 3
// 1651.749 us; speedup vs baseline: 1.5819x; 1.5819x over previous
//
#include <hip/hip_runtime.h>
#include <hip/hip_bf16.h>
#include <cstdint>

#define NHW 65536
#define NSQ 32768

// workspace layout (float slots)
static constexpr size_t OFF_AQ  = 0;          // (4,64,256,128) conv1x1_q at nonanchor (squeezed)
static constexpr size_t OFF_AK  = 8388608;    // (4,64,256,128) conv1x1_k at anchor (squeezed)
static constexpr size_t OFF_AV  = 16777216;   // (4,64,256,256) conv1x1_v full res
static constexpr size_t OFF_EK  = 33554432;   // (4,64,256,128) exp(k_dw) squeezed
static constexpr size_t OFF_VD  = 41943040;   // (4,64,256,128) v_dw squeezed
static constexpr size_t OFF_ATT = 50331648;   // bf16 (4,256,128,64) att squeezed, channel-innermost
static constexpr size_t OFF_CTX = 58720256;   // 4*4*16*16
static constexpr size_t OFF_Z   = 58724352;   // 4*64
static constexpr size_t OFF_RWT = 58724608;   // bf16 wA[tap(25)][c/8(8)][o(128)][c%8(8)] = 204800 ushorts
static constexpr size_t MB2_US  = 67108864;   // ushort offset of mbuf2 (mbuf at 0) - phases don't overlap

typedef __attribute__((ext_vector_type(8))) short short8;
typedef __attribute__((ext_vector_type(4))) float floatx4;

// tap tables: first 13 = even parity (kh+kw even), last 12 = odd parity
__device__ __constant__ int TKH[25] = {0,0,0,1,1,2,2,2,3,3,4,4,4,  0,0,1,1,1,2,2,3,3,3,4,4};
__device__ __constant__ int TKW[25] = {0,2,4,1,3,0,2,4,1,3,0,2,4,  1,3,0,2,4,1,3,0,2,4,1,3};

__device__ __forceinline__ float geluf(float x) {
  return 0.5f * x * (1.0f + erff(x * 0.70710678118654752440f));
}
__device__ __forceinline__ unsigned short f2bf(float f) {
  union { float f; uint32_t u; } v; v.f = f;
  uint32_t x = v.u;
  uint32_t r = x + 0x7fffu + ((x >> 16) & 1u);
  return (unsigned short)(r >> 16);
}
__device__ __forceinline__ float bf2f(unsigned short u) {
  union { uint32_t i; float f; } v; v.i = ((uint32_t)u) << 16; return v.f;
}

// K0: prep conv5 weights into A-fragment order: wA[tap][c/8][o][c%8] bf16
__global__ void __launch_bounds__(256) k0_wprep(const float* __restrict__ rw,
                                                unsigned short* __restrict__ wAu) {
  int idx = blockIdx.x * 256 + threadIdx.x;   // 204800 total
  int cj = idx & 7, o = (idx >> 3) & 127, chunk = (idx >> 10) & 7, tap = idx >> 13;
  int c = chunk * 8 + cj;
  int t = TKH[tap] * 5 + TKW[tap];
  wAu[idx] = f2bf(rw[(o * 64 + c) * 25 + t]);
}

// K1: 1x1 convs. q at nonanchor((i+j)%2==0), k at anchor, v everywhere.
__global__ void __launch_bounds__(256) k1_qkv(
    const float* __restrict__ x1, const float* __restrict__ x2,
    const float* __restrict__ q1w, const float* __restrict__ q1b,
    const float* __restrict__ k1w, const float* __restrict__ k1b,
    const float* __restrict__ v1w, const float* __restrict__ v1b,
    float* ws) {
  __shared__ float wq[4096], wk[4096], wv[4096];
  int tid = threadIdx.x;
  for (int idx = tid; idx < 4096; idx += 256) {
    int o = idx >> 6, c = idx & 63;        // coalesced global reads
    wq[c * 64 + o] = q1w[o * 64 + c];
    wk[c * 64 + o] = k1w[o * 64 + c];
    wv[c * 64 + o] = v1w[o * 64 + c];
  }
  __syncthreads();
  int b = blockIdx.x >> 8, i = blockIdx.x & 255;
  int w = tid >> 6, l = tid & 63;
  int j = (((w >> 1) * 64 + l) << 1) | (w & 1);  // wave-uniform column parity
  int par = (i + j) & 1;                          // 1 = anchor -> k
  const float* wsel = par ? wk : wq;
  const float* bsel = par ? k1b : q1b;
  float acc[64];
#pragma unroll
  for (int o = 0; o < 64; o++) acc[o] = bsel[o];
  const float* xp = x1 + ((size_t)b * 64) * NHW + i * 256 + j;
  for (int c = 0; c < 64; c++) {
    float v = xp[(size_t)c * NHW];
    const float* wr = wsel + c * 64;
#pragma unroll
    for (int o = 0; o < 64; o++) acc[o] += wr[o] * v;
  }
  {
    float* dst = ws + (par ? OFF_AK : OFF_AQ) + ((size_t)b * 64) * NSQ + i * 128 + (j >> 1);
#pragma unroll
    for (int o = 0; o < 64; o++) dst[(size_t)o * NSQ] = acc[o];
  }
#pragma unroll
  for (int o = 0; o < 64; o++) acc[o] = v1b[o];
  const float* xp2 = x2 + ((size_t)b * 64) * NHW + i * 256 + j;
  for (int c = 0; c < 64; c++) {
    float v = xp2[(size_t)c * NHW];
    const float* wr = wv + c * 64;
#pragma unroll
    for (int o = 0; o < 64; o++) acc[o] += wr[o] * v;
  }
  float* dv = ws + OFF_AV + ((size_t)b * 64) * NHW + i * 256 + j;
#pragma unroll
  for (int o = 0; o < 64; o++) dv[(size_t)o * NHW] = acc[o];
}

// K2: k depthwise (5 real taps + bias correction) -> exp; v depthwise (9 taps, full res);
// accumulate Z[b,c] = sum exp(kdw)
__global__ void __launch_bounds__(256) k2_dw(
    float* ws,
    const float* __restrict__ kw2, const float* __restrict__ kb2, const float* __restrict__ kb1,
    const float* __restrict__ vw2, const float* __restrict__ vb2) {
  int bid = blockIdx.x;                 // 4*64*128
  int b = bid >> 13, c = (bid >> 7) & 63, ip = bid & 127;
  int tid = threadIdx.x;
  int i = ip * 2 + (tid >> 7);
  int jp = tid & 127;
  int s = 1 - (i & 1);                  // anchor: col = 2*jp + s
  int j = 2 * jp + s;
  const float* AK = ws + OFF_AK + ((size_t)(b * 64 + c)) * NSQ;
  const float* w9 = kw2 + c * 9;
  float acc = kb2[c] + w9[4] * AK[i * 128 + jp];
  int cl = jp - 1 + s, cr = jp + s;
  if (i > 0) {
    const float* r = AK + (i - 1) * 128;
    if (cl >= 0)   acc += w9[0] * r[cl];
    if (cr <= 127) acc += w9[2] * r[cr];
  }
  if (i < 255) {
    const float* r = AK + (i + 1) * 128;
    if (cl >= 0)   acc += w9[6] * r[cl];
    if (cr <= 127) acc += w9[8] * r[cr];
  }
  float bs = 0.f;
  if (i > 0)   bs += w9[1];
  if (i < 255) bs += w9[7];
  if (j > 0)   bs += w9[3];
  if (j < 255) bs += w9[5];
  acc += kb1[c] * bs;                   // masked neighbors contribute conv1 bias only
  float ek = expf(acc);
  ws[OFF_EK + ((size_t)(b * 64 + c)) * NSQ + i * 128 + jp] = ek;

  const float* AV = ws + OFF_AV + ((size_t)(b * 64 + c)) * NHW;
  const float* vw = vw2 + c * 9;
  float av = vb2[c];
#pragma unroll
  for (int kh = 0; kh < 3; kh++) {
    int r = i - 1 + kh;
    if (r < 0 || r > 255) continue;
    const float* rp = AV + r * 256;
#pragma unroll
    for (int kwd = 0; kwd < 3; kwd++) {
      int u = j - 1 + kwd;
      if (u < 0 || u > 255) continue;
      av += vw[kh * 3 + kwd] * rp[u];
    }
  }
  ws[OFF_VD + ((size_t)(b * 64 + c)) * NSQ + i * 128 + jp] = av;

  __shared__ float red[256];
  red[tid] = ek;
  __syncthreads();
#pragma unroll
  for (int off = 128; off > 0; off >>= 1) {
    if (tid < off) red[tid] += red[tid + off];
    __syncthreads();
  }
  if (tid == 0) atomicAdd(ws + OFF_Z + (b * 64 + c), red[0]);
}

// K3: ctx_raw[b,h,d,e] = sum_n ek[b,h*16+d,n] * vdw[b,h*16+e,n]
__global__ void __launch_bounds__(256) k3_ctx(float* ws) {
  int bid = blockIdx.x;                 // 4*4*8
  int b = bid >> 5, h = (bid >> 3) & 3, ch = bid & 7;
  int n0 = ch * 4096;
  int tid = threadIdx.x;
  int d = tid >> 4, e = tid & 15;
  __shared__ float ekt[16][260];
  __shared__ float vdt[16][260];
  const float* ekb = ws + OFF_EK + ((size_t)(b * 64 + h * 16)) * NSQ + n0;
  const float* vdb = ws + OFF_VD + ((size_t)(b * 64 + h * 16)) * NSQ + n0;
  float acc = 0.f;
  for (int sub = 0; sub < 16; sub++) {
    __syncthreads();
#pragma unroll
    for (int r = 0; r < 16; r++) {
      ekt[r][tid] = ekb[(size_t)r * NSQ + sub * 256 + tid];
      vdt[r][tid] = vdb[(size_t)r * NSQ + sub * 256 + tid];
    }
    __syncthreads();
#pragma unroll 8
    for (int x = 0; x < 256; x++) acc += ekt[d][x] * vdt[e][x];
  }
  atomicAdd(ws + OFF_CTX + ((b * 4 + h) * 16 + d) * 16 + e, acc);
}

// K4: q depthwise + softmax over d, att[e] = sum_d (ctx_raw/Z)[d,e]*qsoft[d];
// store bf16, channel-innermost [b][i][jp][c]
__global__ void __launch_bounds__(256) k4_att(
    float* ws,
    const float* __restrict__ qw2, const float* __restrict__ qb2, const float* __restrict__ qb1) {
  int b = blockIdx.x >> 7, ip = blockIdx.x & 127;
  int tid = threadIdx.x;
  int i = ip * 2 + (tid >> 7);
  int jp = tid & 127;
  __shared__ float ctxn[1024];
  for (int idx = tid; idx < 1024; idx += 256)
    ctxn[idx] = ws[OFF_CTX + b * 1024 + idx] / ws[OFF_Z + b * 64 + (idx >> 4)];
  __syncthreads();
  int s = i & 1;                        // nonanchor: col = 2*jp + s
  int j = 2 * jp + s;
  int cl = jp - 1 + s, cr = jp + s;
  unsigned short* attB = (unsigned short*)(ws + OFF_ATT);
  unsigned short* dstp = attB + (((size_t)(b * 256 + i)) * 128 + jp) * 64;
  for (int h = 0; h < 4; h++) {
    float qv[16];
#pragma unroll
    for (int dc = 0; dc < 16; dc++) {
      int c = h * 16 + dc;
      const float* AQ = ws + OFF_AQ + ((size_t)(b * 64 + c)) * NSQ;
      const float* w9 = qw2 + c * 9;
      float acc = qb2[c] + w9[4] * AQ[i * 128 + jp];
      if (i > 0) {
        const float* r = AQ + (i - 1) * 128;
        if (cl >= 0)   acc += w9[0] * r[cl];
        if (cr <= 127) acc += w9[2] * r[cr];
      }
      if (i < 255) {
        const float* r = AQ + (i + 1) * 128;
        if (cl >= 0)   acc += w9[6] * r[cl];
        if (cr <= 127) acc += w9[8] * r[cr];
      }
      float bs = 0.f;
      if (i > 0)   bs += w9[1];
      if (i < 255) bs += w9[7];
      if (j > 0)   bs += w9[3];
      if (j < 255) bs += w9[5];
      qv[dc] = acc + qb1[c] * bs;
    }
    float mx = qv[0];
#pragma unroll
    for (int dc = 1; dc < 16; dc++) mx = fmaxf(mx, qv[dc]);
    float sum = 0.f;
#pragma unroll
    for (int dc = 0; dc < 16; dc++) { qv[dc] = expf(qv[dc] - mx); sum += qv[dc]; }
    float inv = 1.0f / sum;
#pragma unroll
    for (int e = 0; e < 16; e++) {
      float a = 0.f;
#pragma unroll
      for (int dc = 0; dc < 16; dc++) a += ctxn[h * 256 + dc * 16 + e] * qv[dc];
      dstp[h * 16 + e] = f2bf(a * inv);
    }
  }
}

// K5: 5x5 conv 64->128ch over checkerboard-sparse att, as bf16 MFMA implicit GEMM.
// Per (b, parity): C[o=128][n=128 px (4 rows x 32 jp)] = sum_{tap,c} W[o][tap,c]*Att[tap,c][n].
// attL layout [lr(8)][cb(3)][pos(16)][slot=chunk^(pos&7)][8ch] -> conflict-free b128 r/w.
__global__ void __launch_bounds__(256) k5_mfma(
    const unsigned short* __restrict__ attB, const unsigned short* __restrict__ wAu,
    const float* __restrict__ rb, float* __restrict__ out) {
  int p = blockIdx.y, b = blockIdx.z;
  int i0 = (blockIdx.x >> 2) * 4;
  int jp0 = (blockIdx.x & 3) * 32;
  int tid = threadIdx.x;
  int wv = tid >> 6, lane = tid & 63;
  int mh = wv & 1, nh = wv >> 1;
  int l15 = lane & 15, quad = lane >> 4;

  __shared__ __align__(16) unsigned short attL[24576];  // 48KB: X16=((lr*3+cb)*16+pos)*8+slot
  __shared__ __align__(16) unsigned short wL[8192];     // 16KB: X16=(chalf*4+quad)*128+o

  // stage att tile (8 rows x 48 cols x 64 ch): 3072 16B units
  const unsigned short* attBase = attB + ((size_t)b * 256) * 128 * 64;
  for (int k = 0; k < 12; k++) {
    int u = k * 256 + tid;
    int chunk = u & 7;
    int pos = (u >> 3) & 15;
    int cbr = u >> 7;                  // lr*3+cb, 0..23
    int cb = cbr % 3, lr = cbr / 3;
    int r = i0 - 2 + lr;
    int jp = jp0 - 2 + cb * 16 + pos;
    short8 v = {0, 0, 0, 0, 0, 0, 0, 0};
    if (r >= 0 && r < 256 && jp >= 0 && jp < 128)
      v = *(const short8*)(attBase + (((size_t)r * 128) + jp) * 64 + chunk * 8);
    int slot = chunk ^ (pos & 7);
    *(short8*)(attL + (((size_t)cbr * 16 + pos) * 8 + slot) * 8) = v;
  }

  floatx4 acc[16];
#pragma unroll
  for (int x = 0; x < 16; x++) acc[x] = floatx4{0.f, 0.f, 0.f, 0.f};

  int riv[4], ci2[4];
#pragma unroll
  for (int nt = 0; nt < 4; nt++) {
    int ntg = nh * 4 + nt;
    riv[nt] = ntg >> 1;
    ci2[nt] = (ntg & 1) * 16 + l15 + 2;
  }

  int t0 = p ? 13 : 0;
  int ntaps = p ? 12 : 13;
  for (int tt = 0; tt < ntaps; tt++) {
    int tap = t0 + tt;
    int kh = TKH[tap], kw = TKW[tap];
    __syncthreads();
    {
      const short8* src = (const short8*)(wAu + (size_t)tap * 8192);
      short8* dst = (short8*)wL;
#pragma unroll
      for (int k = 0; k < 4; k++) dst[k * 256 + tid] = src[k * 256 + tid];
    }
    __syncthreads();
#pragma unroll
    for (int chalf = 0; chalf < 2; chalf++) {
      short8 a[4], bf[4];
#pragma unroll
      for (int mt = 0; mt < 4; mt++)
        a[mt] = *(const short8*)(wL + (((chalf * 4 + quad) * 128) + mh * 64 + mt * 16 + l15) * 8);
#pragma unroll
      for (int nt = 0; nt < 4; nt++) {
        int lr = riv[nt] + kh;
        int off = ((kw - 2) + ((p + riv[nt]) & 1) - ((riv[nt] + kh) & 1)) >> 1;
        int lc = ci2[nt] + off;
        int cb = lc >> 4, pos = lc & 15;
        int slot = (chalf * 4 + quad) ^ (pos & 7);
        bf[nt] = *(const short8*)(attL + ((((lr * 3 + cb) * 16 + pos) * 8) + slot) * 8);
      }
#pragma unroll
      for (int mt = 0; mt < 4; mt++)
#pragma unroll
        for (int nt = 0; nt < 4; nt++)
          acc[mt * 4 + nt] =
              __builtin_amdgcn_mfma_f32_16x16x32_bf16(a[mt], bf[nt], acc[mt * 4 + nt], 0, 0, 0);
    }
  }

  // epilogue: D row = o = mh*64+mt*16+quad*4+reg, col = n = lane&15 within n-tile
#pragma unroll
  for (int mt = 0; mt < 4; mt++) {
#pragma unroll
    for (int nt = 0; nt < 4; nt++) {
      int ntg = nh * 4 + nt;
      int i = i0 + (ntg >> 1);
      int jp = jp0 + (ntg & 1) * 16 + l15;
      int j = 2 * jp + ((p + i) & 1);
      floatx4 v = acc[mt * 4 + nt];
#pragma unroll
      for (int r = 0; r < 4; r++) {
        int o = mh * 64 + mt * 16 + quad * 4 + r;
        out[(((size_t)(b * 128 + o)) * 256 + i) * 256 + j] = v[r] + rb[o];
      }
    }
  }
}

// K6: m1 = gelu(conv1x1 128->256) ; fp32 in (d_out), bf16 out
__global__ void __launch_bounds__(256) k6_m1(
    const float* __restrict__ attn, const float* __restrict__ m1w, const float* __restrict__ m1b,
    unsigned short* __restrict__ mb) {
  int n0 = blockIdx.x * 64;
  int og = blockIdx.y, b = blockIdx.z;
  int tid = threadIdx.x;
  int ot = tid >> 4, pt = tid & 15;
  __shared__ __align__(16) float aL[2048];
  __shared__ __align__(16) float wL[32 * 68];
  float acc[4][4];
#pragma unroll
  for (int x = 0; x < 4; x++)
#pragma unroll
    for (int y = 0; y < 4; y++) acc[x][y] = 0.f;
  for (int cc = 0; cc < 128; cc += 32) {
    __syncthreads();
#pragma unroll
    for (int k = 0; k < 8; k++) {
      int idx = k * 256 + tid;
      int ci = idx >> 6, pp = idx & 63;
      aL[ci * 64 + pp] = attn[((size_t)(b * 128 + cc + ci)) * NHW + n0 + pp];
      int o = idx >> 5, ci2 = idx & 31;
      wL[ci2 * 68 + o] = m1w[(og * 64 + o) * 128 + cc + ci2];
    }
    __syncthreads();
    for (int ci = 0; ci < 32; ci++) {
      float4 a4 = *(const float4*)(aL + ci * 64 + pt * 4);
      float4 w4 = *(const float4*)(wL + ci * 68 + ot * 4);
      acc[0][0] += w4.x * a4.x; acc[0][1] += w4.x * a4.y; acc[0][2] += w4.x * a4.z; acc[0][3] += w4.x * a4.w;
      acc[1][0] += w4.y * a4.x; acc[1][1] += w4.y * a4.y; acc[1][2] += w4.y * a4.z; acc[1][3] += w4.y * a4.w;
      acc[2][0] += w4.z * a4.x; acc[2][1] += w4.z * a4.y; acc[2][2] += w4.z * a4.z; acc[2][3] += w4.z * a4.w;
      acc[3][0] += w4.w * a4.x; acc[3][1] += w4.w * a4.y; acc[3][2] += w4.w * a4.z; acc[3][3] += w4.w * a4.w;
    }
  }
#pragma unroll
  for (int oi = 0; oi < 4; oi++) {
    int o = og * 64 + ot * 4 + oi;
    float bo = m1b[o];
    ushort4 u;
    u.x = f2bf(geluf(acc[oi][0] + bo));
    u.y = f2bf(geluf(acc[oi][1] + bo));
    u.z = f2bf(geluf(acc[oi][2] + bo));
    u.w = f2bf(geluf(acc[oi][3] + bo));
    *(ushort4*)(mb + ((size_t)(b * 256 + o)) * NHW + n0 + pt * 4) = u;
  }
}

// K7: m2 = gelu(depthwise 3x3 on 256ch), bf16 -> bf16
__global__ void __launch_bounds__(256) k7_m2(
    const unsigned short* __restrict__ mb, const float* __restrict__ m2w,
    const float* __restrict__ m2b, unsigned short* __restrict__ mb2) {
  int bid = blockIdx.x;
  int b = bid >> 16, c = (bid >> 8) & 255, i = bid & 255;
  int j = threadIdx.x;
  const unsigned short* base = mb + ((size_t)(b * 256 + c)) * NHW;
  const float* w9 = m2w + c * 9;
  float acc = m2b[c];
#pragma unroll
  for (int kh = 0; kh < 3; kh++) {
    int r = i - 1 + kh;
    if (r < 0 || r > 255) continue;
#pragma unroll
    for (int kw = 0; kw < 3; kw++) {
      int u = j - 1 + kw;
      if (u < 0 || u > 255) continue;
      acc += w9[kh * 3 + kw] * bf2f(base[r * 256 + u]);
    }
  }
  mb2[((size_t)(b * 256 + c)) * NHW + i * 256 + j] = f2bf(geluf(acc));
}

// K8: out = attention + conv1x1(m2, 256->128) + m3_b ; bf16 in, fp32 in/out (d_out)
__global__ void __launch_bounds__(256) k8_m3(
    const unsigned short* __restrict__ mb2, const float* __restrict__ m3w,
    const float* __restrict__ m3b, float* __restrict__ out) {
  int n0 = blockIdx.x * 64;
  int og = blockIdx.y, b = blockIdx.z;
  int tid = threadIdx.x;
  int ot = tid >> 4, pt = tid & 15;
  __shared__ __align__(16) float aL[2048];
  __shared__ __align__(16) float wL[32 * 68];
  float acc[4][4];
#pragma unroll
  for (int x = 0; x < 4; x++)
#pragma unroll
    for (int y = 0; y < 4; y++) acc[x][y] = 0.f;
  for (int cc = 0; cc < 256; cc += 32) {
    __syncthreads();
#pragma unroll
    for (int k = 0; k < 2; k++) {
      int e4 = (k * 256 + tid) * 4;
      int ci = e4 >> 6, p0 = e4 & 63;
      const ushort4 uv = *(const ushort4*)(mb2 + ((size_t)(b * 256 + cc + ci)) * NHW + n0 + p0);
      aL[ci * 64 + p0 + 0] = bf2f(uv.x);
      aL[ci * 64 + p0 + 1] = bf2f(uv.y);
      aL[ci * 64 + p0 + 2] = bf2f(uv.z);
      aL[ci * 64 + p0 + 3] = bf2f(uv.w);
    }
#pragma unroll
    for (int k = 0; k < 8; k++) {
      int idx = k * 256 + tid;
      int o = idx >> 5, ci2 = idx & 31;
      wL[ci2 * 68 + o] = m3w[(og * 64 + o) * 256 + cc + ci2];
    }
    __syncthreads();
    for (int ci = 0; ci < 32; ci++) {
      float4 a4 = *(const float4*)(aL + ci * 64 + pt * 4);
      float4 w4 = *(const float4*)(wL + ci * 68 + ot * 4);
      acc[0][0] += w4.x * a4.x; acc[0][1] += w4.x * a4.y; acc[0][2] += w4.x * a4.z; acc[0][3] += w4.x * a4.w;
      acc[1][0] += w4.y * a4.x; acc[1][1] += w4.y * a4.y; acc[1][2] += w4.y * a4.z; acc[1][3] += w4.y * a4.w;
      acc[2][0] += w4.z * a4.x; acc[2][1] += w4.z * a4.y; acc[2][2] += w4.z * a4.z; acc[2][3] += w4.z * a4.w;
      acc[3][0] += w4.w * a4.x; acc[3][1] += w4.w * a4.y; acc[3][2] += w4.w * a4.z; acc[3][3] += w4.w * a4.w;
    }
  }
#pragma unroll
  for (int oi = 0; oi < 4; oi++) {
    int o = og * 64 + ot * 4 + oi;
    float bo = m3b[o];
    size_t addr = ((size_t)(b * 128 + o)) * NHW + n0 + pt * 4;
    float4 prev = *(const float4*)(out + addr);
    float4 res;
    res.x = prev.x + acc[oi][0] + bo;
    res.y = prev.y + acc[oi][1] + bo;
    res.z = prev.z + acc[oi][2] + bo;
    res.w = prev.w + acc[oi][3] + bo;
    *(float4*)(out + addr) = res;
  }
}

extern "C" void kernel_launch(void* const* d_in, const int* in_sizes, int n_in,
                              void* d_out, int out_size, void* d_ws, size_t ws_size,
                              hipStream_t stream) {
  const float* x1  = (const float*)d_in[0];
  const float* x2  = (const float*)d_in[1];
  const float* q1w = (const float*)d_in[2];  const float* q1b = (const float*)d_in[3];
  const float* q2w = (const float*)d_in[4];  const float* q2b = (const float*)d_in[5];
  const float* k1w = (const float*)d_in[6];  const float* k1b = (const float*)d_in[7];
  const float* k2w = (const float*)d_in[8];  const float* k2b = (const float*)d_in[9];
  const float* v1w = (const float*)d_in[10]; const float* v1b = (const float*)d_in[11];
  const float* v2w = (const float*)d_in[12]; const float* v2b = (const float*)d_in[13];
  const float* rw  = (const float*)d_in[14]; const float* rb  = (const float*)d_in[15];
  const float* m1w = (const float*)d_in[16]; const float* m1b = (const float*)d_in[17];
  const float* m2w = (const float*)d_in[18]; const float* m2b = (const float*)d_in[19];
  const float* m3w = (const float*)d_in[20]; const float* m3b = (const float*)d_in[21];
  float* ws = (float*)d_ws;
  float* out = (float*)d_out;
  unsigned short* mb  = (unsigned short*)d_ws;
  unsigned short* mb2 = (unsigned short*)d_ws + MB2_US;
  unsigned short* attB = (unsigned short*)(ws + OFF_ATT);
  unsigned short* wAu  = (unsigned short*)(ws + OFF_RWT);

  (void)hipMemsetAsync((char*)d_ws + OFF_CTX * sizeof(float), 0, (4096 + 256) * sizeof(float), stream);
  k0_wprep<<<800, 256, 0, stream>>>(rw, wAu);
  k1_qkv<<<1024, 256, 0, stream>>>(x1, x2, q1w, q1b, k1w, k1b, v1w, v1b, ws);
  k2_dw<<<32768, 256, 0, stream>>>(ws, k2w, k2b, k1b, v2w, v2b);
  k3_ctx<<<128, 256, 0, stream>>>(ws);
  k4_att<<<512, 256, 0, stream>>>(ws, q2w, q2b, q1b);
  k5_mfma<<<dim3(256, 2, 4), 256, 0, stream>>>(attB, wAu, rb, out);
  k6_m1<<<dim3(1024, 4, 4), 256, 0, stream>>>(out, m1w, m1b, mb);
  k7_m2<<<262144, 256, 0, stream>>>(mb, m2w, m2b, mb2);
  k8_m3<<<dim3(1024, 2, 4), 256, 0, stream>>>(mb2, m3w, m3b, out);
}